// Round 1
// baseline (353.445 us; speedup 1.0000x reference)
//
#include <hip/hip_runtime.h>
#include <math.h>

#define N 8192
#define D 128
#define MARGIN 0.2f
#define PD_EPS 1e-6f
#define NCHUNK 32
#define CHUNKJ (N / NCHUNK)   // 256 j per chunk

typedef __attribute__((ext_vector_type(8))) short bf16x8;  // 8 bf16 = 4 VGPRs
typedef __attribute__((ext_vector_type(4))) float f32x4;

__device__ __forceinline__ unsigned short f2bf(float f) {
    unsigned u = __float_as_uint(f);
    u += 0x7FFFu + ((u >> 16) & 1u);   // round-to-nearest-even
    return (unsigned short)(u >> 16);
}
__device__ __forceinline__ unsigned umn(unsigned a, unsigned b) { return a < b ? a : b; }
__device__ __forceinline__ unsigned umx(unsigned a, unsigned b) { return a > b ? a : b; }

// ---------------- kernel 1: normalize -> bf16 rows + inv-norm + packed meta ---
__global__ __launch_bounds__(256) void k_normalize(const float* __restrict__ z,
                                                   const int* __restrict__ labels,
                                                   const int* __restrict__ subjects,
                                                   unsigned short* __restrict__ znb,
                                                   float* __restrict__ invn,
                                                   int* __restrict__ meta,
                                                   unsigned* __restrict__ tick) {
    if (blockIdx.x == 0 && threadIdx.x == 0) *tick = 0u;  // re-arm k_final's counter each launch
    int row  = blockIdx.x * 4 + (threadIdx.x >> 6);
    int lane = threadIdx.x & 63;
    float2 v = ((const float2*)(z + (size_t)row * D))[lane];
    float ss = v.x * v.x + v.y * v.y;
    #pragma unroll
    for (int m = 1; m < 64; m <<= 1) ss += __shfl_xor(ss, m, 64);
    float norm = fmaxf(sqrtf(ss), 1e-12f);
    float ox = v.x / norm, oy = v.y / norm;
    ushort2 b; b.x = f2bf(ox); b.y = f2bf(oy);
    ((ushort2*)(znb + (size_t)row * D))[lane] = b;
    if (lane == 0) {
        invn[row] = 1.0f / norm;
        meta[row] = labels[row] * 32 + subjects[row];   // 9 bits: label(4)|subject(5)
    }
}

// ---------------- kernel 2: MFMA mining --------------------------------------
// Wave owns 64 anchors (4 utiles of 16x16x32 MFMA); sweeps CHUNKJ js in 64-wide
// tiles. Since rows are unit-norm, hardest-pos = min dot, hardest-neg = max dot.
// Key = (bits(dot+2) & ~8191) | j  -> min/max carries the argindex.
// NCHUNK=32 -> grid 32x32 = 1024 blocks = exactly 4 blocks/CU (VGPR=128 cap),
// doubling resident waves/SIMD 2->4 vs the 512-block version (latency-bound fix).
__global__ __launch_bounds__(256, 4) void k_mine(const unsigned short* __restrict__ znb,
                                                 const int* __restrict__ meta,
                                                 unsigned* __restrict__ posk,
                                                 unsigned* __restrict__ negk) {
    const int wave = threadIdx.x >> 6;
    const int lane = threadIdx.x & 63;
    const int m    = lane & 15;     // A/B operand row within 16-tile
    const int quad = lane >> 4;     // k-half selector / C-row group
    const int iw   = (blockIdx.x * 4 + wave) * 64;
    const int jc   = blockIdx.y;
    const int jbase = jc * CHUNKJ;

    // persistent A fragments: [utile][kstep], lane holds row iw+u*16+m,
    // k = s*32 + quad*8 .. +8  (A[m=lane&15][k=quad*8+j] layout, m89-verified)
    bf16x8 afrag[4][4];
    #pragma unroll
    for (int u = 0; u < 4; ++u)
        #pragma unroll
        for (int s = 0; s < 4; ++s)
            afrag[u][s] = *(const bf16x8*)(znb + (size_t)(iw + u * 16 + m) * D + s * 32 + quad * 8);

    // meta for this lane's 16 C-row slots: i = iw + u*16 + quad*4 + r
    int mi[16];
    #pragma unroll
    for (int u = 0; u < 4; ++u)
        #pragma unroll
        for (int r = 0; r < 4; ++r)
            mi[u * 4 + r] = meta[iw + u * 16 + quad * 4 + r];

    unsigned bp[16], bn[16];
    #pragma unroll
    for (int s = 0; s < 16; ++s) { bp[s] = 0xFFFFFFFFu; bn[s] = 0u; }

    for (int t = 0; t < CHUNKJ / 64; ++t) {
        const int jt = jbase + t * 64;

        // hoist the j-metadata loads so they overlap the MFMA block
        int mjv[4];
        #pragma unroll
        for (int v = 0; v < 4; ++v) mjv[v] = meta[jt + v * 16 + m];

        f32x4 acc[4][4];
        #pragma unroll
        for (int u = 0; u < 4; ++u)
            #pragma unroll
            for (int v = 0; v < 4; ++v)
                acc[u][v] = (f32x4){0.f, 0.f, 0.f, 0.f};

        #pragma unroll
        for (int s = 0; s < 4; ++s) {
            bf16x8 bf[4];
            #pragma unroll
            for (int v = 0; v < 4; ++v)
                bf[v] = *(const bf16x8*)(znb + (size_t)(jt + v * 16 + m) * D + s * 32 + quad * 8);
            #pragma unroll
            for (int u = 0; u < 4; ++u)
                #pragma unroll
                for (int v = 0; v < 4; ++v)
                    acc[u][v] = __builtin_amdgcn_mfma_f32_16x16x32_bf16(afrag[u][s], bf[v], acc[u][v], 0, 0, 0);
        }

        // epilogue: C/D layout col=lane&15, row=quad*4+reg (m89/m91-verified)
        #pragma unroll
        for (int v = 0; v < 4; ++v) {
            const int jv = jt + v * 16 + m;     // this lane's j for tile v
            #pragma unroll
            for (int u = 0; u < 4; ++u)
                #pragma unroll
                for (int r = 0; r < 4; ++r) {
                    float dot = acc[u][v][r];
                    unsigned key = (__float_as_uint(dot + 2.0f) & 0xFFFFE000u) | (unsigned)jv;
                    int x = mi[u * 4 + r] ^ mjv[v];
                    bool pos = (x != 0) && (x < 32);          // same class, diff subject
                    bool neg = (x != 0) && ((x & 31) == 0);   // diff class, same subject
                    bp[u * 4 + r] = umn(bp[u * 4 + r], pos ? key : 0xFFFFFFFFu);
                    bn[u * 4 + r] = umx(bn[u * 4 + r], neg ? key : 0u);
                }
        }
    }

    // merge across the 16 lanes (different j) sharing each (quad, slot)
    #pragma unroll
    for (int mm = 1; mm < 16; mm <<= 1)
        #pragma unroll
        for (int s = 0; s < 16; ++s) {
            bp[s] = umn(bp[s], (unsigned)__shfl_xor((int)bp[s], mm, 64));
            bn[s] = umx(bn[s], (unsigned)__shfl_xor((int)bn[s], mm, 64));
        }
    if (m == 0) {
        #pragma unroll
        for (int u = 0; u < 4; ++u)
            #pragma unroll
            for (int r = 0; r < 4; ++r) {
                int i = iw + u * 16 + quad * 4 + r;
                posk[(size_t)jc * N + i] = bp[u * 4 + r];
                negk[(size_t)jc * N + i] = bn[u * 4 + r];
            }
    }
}

// ---------------- kernel 3: combine chunks + fp32 hinge + last-block reduce --
__global__ __launch_bounds__(256) void k_final(const float* __restrict__ z,
                                               const float* __restrict__ invn,
                                               const unsigned* __restrict__ posk,
                                               const unsigned* __restrict__ negk,
                                               float* __restrict__ per, float* __restrict__ vld,
                                               unsigned* __restrict__ tick,
                                               float* __restrict__ out) {
    __shared__ float s1[256], s2[256];
    __shared__ int lastFlag;
    int row  = blockIdx.x * 4 + (threadIdx.x >> 6);
    int lane = threadIdx.x & 63;
    unsigned mp = 0xFFFFFFFFu, mn = 0u;
    #pragma unroll
    for (int c = 0; c < NCHUNK; ++c) {
        mp = umn(mp, posk[(size_t)c * N + row]);
        mn = umx(mn, negk[(size_t)c * N + row]);
    }
    bool valid = (mp != 0xFFFFFFFFu) && (mn != 0u);
    int pi = valid ? (int)(mp & 8191u) : 0;
    int ni = valid ? (int)(mn & 8191u) : 0;
    float ia = invn[row], ip = invn[pi], iq = invn[ni];
    float2 a = ((const float2*)(z + (size_t)row * D))[lane];
    float2 p = ((const float2*)(z + (size_t)pi  * D))[lane];
    float2 q = ((const float2*)(z + (size_t)ni  * D))[lane];
    float dx = a.x * ia - p.x * ip + PD_EPS, dy = a.y * ia - p.y * ip + PD_EPS;
    float sap = dx * dx + dy * dy;
    dx = a.x * ia - q.x * iq + PD_EPS; dy = a.y * ia - q.y * iq + PD_EPS;
    float san = dx * dx + dy * dy;
    #pragma unroll
    for (int m = 1; m < 64; m <<= 1) {
        sap += __shfl_xor(sap, m, 64);
        san += __shfl_xor(san, m, 64);
    }
    if (lane == 0) {
        float l = fmaxf(sqrtf(sap) - sqrtf(san) + MARGIN, 0.0f);
        per[row] = valid ? l : 0.0f;
        vld[row] = valid ? 1.0f : 0.0f;
    }

    // ---- last-block-done deterministic reduce (replaces k_reduce launch) ----
    __threadfence();           // release our per/vld writes (device scope)
    __syncthreads();           // all 4 rows of this block written before counting
    if (threadIdx.x == 0)
        lastFlag = (atomicAdd(tick, 1u) == gridDim.x - 1);
    __syncthreads();
    if (lastFlag) {
        __threadfence();       // acquire: see all other blocks' per/vld
        int t = threadIdx.x;
        float a2 = 0.f, b2 = 0.f;
        for (int i = t; i < N; i += 256) { a2 += per[i]; b2 += vld[i]; }
        s1[t] = a2; s2[t] = b2;
        __syncthreads();
        for (int w = 128; w > 0; w >>= 1) {
            if (t < w) { s1[t] += s1[t + w]; s2[t] += s2[t + w]; }
            __syncthreads();
        }
        if (t == 0) {
            float cnt = s2[0];
            out[0] = (cnt > 0.f) ? s1[0] / fmaxf(cnt, 1.f) : 0.f;
            *tick = 0u;        // defensive re-arm (also zeroed by k_normalize)
        }
    }
}

extern "C" void kernel_launch(void* const* d_in, const int* in_sizes, int n_in,
                              void* d_out, int out_size, void* d_ws, size_t ws_size,
                              hipStream_t stream) {
    const float* z        = (const float*)d_in[0];
    const int*   labels   = (const int*)d_in[1];
    const int*   subjects = (const int*)d_in[2];
    float* out = (float*)d_out;

    char* ws = (char*)d_ws;
    unsigned short* znb = (unsigned short*)(ws);            // 2 MB
    float*    invn = (float*)   (ws + 2097152);             // 32 KB
    int*      meta = (int*)     (ws + 2129920);             // 32 KB
    unsigned* posk = (unsigned*)(ws + 2162688);             // 1 MB  (32 chunks)
    unsigned* negk = (unsigned*)(ws + 3211264);             // 1 MB
    float*    per  = (float*)   (ws + 4259840);             // 32 KB
    float*    vld  = (float*)   (ws + 4292608);             // 32 KB
    unsigned* tick = (unsigned*)(ws + 4325376);             // 4 B

    k_normalize<<<dim3(N / 4), dim3(256), 0, stream>>>(z, labels, subjects, znb, invn, meta, tick);
    k_mine<<<dim3(32, NCHUNK), dim3(256), 0, stream>>>(znb, meta, posk, negk);
    k_final<<<dim3(N / 4), dim3(256), 0, stream>>>(z, invn, posk, negk, per, vld, tick, out);
}

// Round 2
// 137.753 us; speedup vs baseline: 2.5658x; 2.5658x over previous
//
#include <hip/hip_runtime.h>
#include <math.h>

#define N 8192
#define D 128
#define MARGIN 0.2f
#define PD_EPS 1e-6f
#define NCHUNK 32
#define CHUNKJ (N / NCHUNK)   // 256 j per chunk

typedef __attribute__((ext_vector_type(8))) short bf16x8;  // 8 bf16 = 4 VGPRs
typedef __attribute__((ext_vector_type(4))) float f32x4;

__device__ __forceinline__ unsigned short f2bf(float f) {
    unsigned u = __float_as_uint(f);
    u += 0x7FFFu + ((u >> 16) & 1u);   // round-to-nearest-even
    return (unsigned short)(u >> 16);
}
__device__ __forceinline__ unsigned umn(unsigned a, unsigned b) { return a < b ? a : b; }
__device__ __forceinline__ unsigned umx(unsigned a, unsigned b) { return a > b ? a : b; }

// ---------------- kernel 1: normalize -> bf16 rows + inv-norm + packed meta ---
__global__ __launch_bounds__(256) void k_normalize(const float* __restrict__ z,
                                                   const int* __restrict__ labels,
                                                   const int* __restrict__ subjects,
                                                   unsigned short* __restrict__ znb,
                                                   float* __restrict__ invn,
                                                   int* __restrict__ meta) {
    int row  = blockIdx.x * 4 + (threadIdx.x >> 6);
    int lane = threadIdx.x & 63;
    float2 v = ((const float2*)(z + (size_t)row * D))[lane];
    float ss = v.x * v.x + v.y * v.y;
    #pragma unroll
    for (int m = 1; m < 64; m <<= 1) ss += __shfl_xor(ss, m, 64);
    float norm = fmaxf(sqrtf(ss), 1e-12f);
    float ox = v.x / norm, oy = v.y / norm;
    ushort2 b; b.x = f2bf(ox); b.y = f2bf(oy);
    ((ushort2*)(znb + (size_t)row * D))[lane] = b;
    if (lane == 0) {
        invn[row] = 1.0f / norm;
        meta[row] = labels[row] * 32 + subjects[row];   // 9 bits: label(4)|subject(5)
    }
}

// ---------------- kernel 2: MFMA mining --------------------------------------
// Wave owns 64 anchors (4 utiles of 16x16x32 MFMA); sweeps CHUNKJ js in 64-wide
// tiles. Since rows are unit-norm, hardest-pos = min dot, hardest-neg = max dot.
// Key = (bits(dot+2) & ~8191) | j  -> min/max carries the argindex.
// launch_bounds (256,2): proven to give exactly 128 VGPR (no spill); do NOT
// raise the waves/EU hint — (256,4) squeezed to 64 VGPR and spilled 230 GB of
// scratch traffic (round-1 post-mortem). Occupancy comes from the GRID instead:
// NCHUNK=32 -> 32x32 = 1024 blocks = exactly 4 blocks/CU at the 128-VGPR budget.
__global__ __launch_bounds__(256, 2) void k_mine(const unsigned short* __restrict__ znb,
                                                 const int* __restrict__ meta,
                                                 unsigned* __restrict__ posk,
                                                 unsigned* __restrict__ negk) {
    const int wave = threadIdx.x >> 6;
    const int lane = threadIdx.x & 63;
    const int m    = lane & 15;     // A/B operand row within 16-tile
    const int quad = lane >> 4;     // k-half selector / C-row group
    const int iw   = (blockIdx.x * 4 + wave) * 64;
    const int jc   = blockIdx.y;
    const int jbase = jc * CHUNKJ;

    // persistent A fragments: [utile][kstep], lane holds row iw+u*16+m,
    // k = s*32 + quad*8 .. +8  (A[m=lane&15][k=quad*8+j] layout, m89-verified)
    bf16x8 afrag[4][4];
    #pragma unroll
    for (int u = 0; u < 4; ++u)
        #pragma unroll
        for (int s = 0; s < 4; ++s)
            afrag[u][s] = *(const bf16x8*)(znb + (size_t)(iw + u * 16 + m) * D + s * 32 + quad * 8);

    // meta for this lane's 16 C-row slots: i = iw + u*16 + quad*4 + r
    int mi[16];
    #pragma unroll
    for (int u = 0; u < 4; ++u)
        #pragma unroll
        for (int r = 0; r < 4; ++r)
            mi[u * 4 + r] = meta[iw + u * 16 + quad * 4 + r];

    unsigned bp[16], bn[16];
    #pragma unroll
    for (int s = 0; s < 16; ++s) { bp[s] = 0xFFFFFFFFu; bn[s] = 0u; }

    for (int t = 0; t < CHUNKJ / 64; ++t) {
        const int jt = jbase + t * 64;

        // hoist the j-metadata loads so they overlap the MFMA block
        int mjv[4];
        #pragma unroll
        for (int v = 0; v < 4; ++v) mjv[v] = meta[jt + v * 16 + m];

        f32x4 acc[4][4];
        #pragma unroll
        for (int u = 0; u < 4; ++u)
            #pragma unroll
            for (int v = 0; v < 4; ++v)
                acc[u][v] = (f32x4){0.f, 0.f, 0.f, 0.f};

        #pragma unroll
        for (int s = 0; s < 4; ++s) {
            bf16x8 bf[4];
            #pragma unroll
            for (int v = 0; v < 4; ++v)
                bf[v] = *(const bf16x8*)(znb + (size_t)(jt + v * 16 + m) * D + s * 32 + quad * 8);
            #pragma unroll
            for (int u = 0; u < 4; ++u)
                #pragma unroll
                for (int v = 0; v < 4; ++v)
                    acc[u][v] = __builtin_amdgcn_mfma_f32_16x16x32_bf16(afrag[u][s], bf[v], acc[u][v], 0, 0, 0);
        }

        // epilogue: C/D layout col=lane&15, row=quad*4+reg (m89/m91-verified)
        #pragma unroll
        for (int v = 0; v < 4; ++v) {
            const int jv = jt + v * 16 + m;     // this lane's j for tile v
            #pragma unroll
            for (int u = 0; u < 4; ++u)
                #pragma unroll
                for (int r = 0; r < 4; ++r) {
                    float dot = acc[u][v][r];
                    unsigned key = (__float_as_uint(dot + 2.0f) & 0xFFFFE000u) | (unsigned)jv;
                    int x = mi[u * 4 + r] ^ mjv[v];
                    bool pos = (x != 0) && (x < 32);          // same class, diff subject
                    bool neg = (x != 0) && ((x & 31) == 0);   // diff class, same subject
                    bp[u * 4 + r] = umn(bp[u * 4 + r], pos ? key : 0xFFFFFFFFu);
                    bn[u * 4 + r] = umx(bn[u * 4 + r], neg ? key : 0u);
                }
        }
    }

    // merge across the 16 lanes (different j) sharing each (quad, slot)
    #pragma unroll
    for (int mm = 1; mm < 16; mm <<= 1)
        #pragma unroll
        for (int s = 0; s < 16; ++s) {
            bp[s] = umn(bp[s], (unsigned)__shfl_xor((int)bp[s], mm, 64));
            bn[s] = umx(bn[s], (unsigned)__shfl_xor((int)bn[s], mm, 64));
        }
    if (m == 0) {
        #pragma unroll
        for (int u = 0; u < 4; ++u)
            #pragma unroll
            for (int r = 0; r < 4; ++r) {
                int i = iw + u * 16 + quad * 4 + r;
                posk[(size_t)jc * N + i] = bp[u * 4 + r];
                negk[(size_t)jc * N + i] = bn[u * 4 + r];
            }
    }
}

// ---------------- kernel 3: combine chunks + fp32 hinge ----------------------
__global__ __launch_bounds__(256) void k_final(const float* __restrict__ z,
                                               const float* __restrict__ invn,
                                               const unsigned* __restrict__ posk,
                                               const unsigned* __restrict__ negk,
                                               float* __restrict__ per, float* __restrict__ vld) {
    int row  = blockIdx.x * 4 + (threadIdx.x >> 6);
    int lane = threadIdx.x & 63;
    unsigned mp = 0xFFFFFFFFu, mn = 0u;
    #pragma unroll
    for (int c = 0; c < NCHUNK; ++c) {
        mp = umn(mp, posk[(size_t)c * N + row]);
        mn = umx(mn, negk[(size_t)c * N + row]);
    }
    bool valid = (mp != 0xFFFFFFFFu) && (mn != 0u);
    int pi = valid ? (int)(mp & 8191u) : 0;
    int ni = valid ? (int)(mn & 8191u) : 0;
    float ia = invn[row], ip = invn[pi], iq = invn[ni];
    float2 a = ((const float2*)(z + (size_t)row * D))[lane];
    float2 p = ((const float2*)(z + (size_t)pi  * D))[lane];
    float2 q = ((const float2*)(z + (size_t)ni  * D))[lane];
    float dx = a.x * ia - p.x * ip + PD_EPS, dy = a.y * ia - p.y * ip + PD_EPS;
    float sap = dx * dx + dy * dy;
    dx = a.x * ia - q.x * iq + PD_EPS; dy = a.y * ia - q.y * iq + PD_EPS;
    float san = dx * dx + dy * dy;
    #pragma unroll
    for (int m = 1; m < 64; m <<= 1) {
        sap += __shfl_xor(sap, m, 64);
        san += __shfl_xor(san, m, 64);
    }
    if (lane == 0) {
        float l = fmaxf(sqrtf(sap) - sqrtf(san) + MARGIN, 0.0f);
        per[row] = valid ? l : 0.0f;
        vld[row] = valid ? 1.0f : 0.0f;
    }
}

// ---------------- kernel 4: deterministic final reduce -----------------------
__global__ __launch_bounds__(256) void k_reduce(const float* __restrict__ per,
                                                const float* __restrict__ vld,
                                                float* __restrict__ out) {
    __shared__ float s1[256], s2[256];
    int t = threadIdx.x;
    float a = 0.f, b = 0.f;
    for (int i = t; i < N; i += 256) { a += per[i]; b += vld[i]; }
    s1[t] = a; s2[t] = b;
    __syncthreads();
    for (int w = 128; w > 0; w >>= 1) {
        if (t < w) { s1[t] += s1[t + w]; s2[t] += s2[t + w]; }
        __syncthreads();
    }
    if (t == 0) {
        float cnt = s2[0];
        out[0] = (cnt > 0.f) ? s1[0] / fmaxf(cnt, 1.f) : 0.f;
    }
}

extern "C" void kernel_launch(void* const* d_in, const int* in_sizes, int n_in,
                              void* d_out, int out_size, void* d_ws, size_t ws_size,
                              hipStream_t stream) {
    const float* z        = (const float*)d_in[0];
    const int*   labels   = (const int*)d_in[1];
    const int*   subjects = (const int*)d_in[2];
    float* out = (float*)d_out;

    char* ws = (char*)d_ws;
    unsigned short* znb = (unsigned short*)(ws);            // 2 MB
    float*    invn = (float*)   (ws + 2097152);             // 32 KB
    int*      meta = (int*)     (ws + 2129920);             // 32 KB
    unsigned* posk = (unsigned*)(ws + 2162688);             // 1 MB  (32 chunks)
    unsigned* negk = (unsigned*)(ws + 3211264);             // 1 MB
    float*    per  = (float*)   (ws + 4259840);             // 32 KB
    float*    vld  = (float*)   (ws + 4292608);             // 32 KB

    k_normalize<<<dim3(N / 4), dim3(256), 0, stream>>>(z, labels, subjects, znb, invn, meta);
    k_mine<<<dim3(32, NCHUNK), dim3(256), 0, stream>>>(znb, meta, posk, negk);
    k_final<<<dim3(N / 4), dim3(256), 0, stream>>>(z, invn, posk, negk, per, vld);
    k_reduce<<<dim3(1), dim3(256), 0, stream>>>(per, vld, out);
}